// Round 7
// baseline (4738.691 us; speedup 1.0000x reference)
//
#include <hip/hip_runtime.h>
#include <hip/hip_bf16.h>

typedef unsigned short u16;
typedef unsigned int u32;
typedef __attribute__((ext_vector_type(8))) short short8;
typedef __attribute__((ext_vector_type(4))) float f32x4;
typedef __attribute__((ext_vector_type(16))) float f32x16;

#define GLD_LDS(gptr, lptr) \
    __builtin_amdgcn_global_load_lds((const __attribute__((address_space(1))) void*)(gptr), \
                                     (__attribute__((address_space(3))) void*)(lptr), 16, 0, 0)

__device__ __forceinline__ u32 bf16_rne(float f) {
    u32 u = __float_as_uint(f);
    return (u + 0x7FFFu + ((u >> 16) & 1u)) >> 16;
}

// column permutation: orig col c = k*4096 + g*1024 + hx  ->  n = hx*16 + k*4 + g
__device__ __forceinline__ int permcol(int c) {
    return (c & 1023) * 16 + ((c >> 12) & 3) * 4 + ((c >> 10) & 3);
}

__device__ __forceinline__ float sigf(float x) { return 1.0f / (1.0f + expf(-x)); }

// ---------------------------------------------------------------------------
// Transpose + split fp32 [1024][N] -> bf16 hi/lo [N'][1024] row-major
// ---------------------------------------------------------------------------
template <bool PERM>
__global__ __launch_bounds__(256) void transpose_split(
    const float* __restrict__ W, u16* __restrict__ Thi, u16* __restrict__ Tlo, int N)
{
    __shared__ float tile[64][65];
    int n0 = blockIdx.x * 64;
    int k0 = blockIdx.y * 64;
    int tid = threadIdx.x;
    int tr = tid >> 4;      // 0..15
    int tc = tid & 15;      // 0..15
#pragma unroll
    for (int it = 0; it < 4; ++it) {
        int kr = it * 16 + tr;
        const float4* src = (const float4*)&W[(size_t)(k0 + kr) * N + n0 + tc * 4];
        float4 v = *src;
        tile[kr][tc * 4 + 0] = v.x;
        tile[kr][tc * 4 + 1] = v.y;
        tile[kr][tc * 4 + 2] = v.z;
        tile[kr][tc * 4 + 3] = v.w;
    }
    __syncthreads();
#pragma unroll
    for (int it = 0; it < 4; ++it) {
        int nr = it * 16 + tr;
        u32 h[4], l[4];
#pragma unroll
        for (int j = 0; j < 4; ++j) {
            float f = tile[tc * 4 + j][nr];
            u32 hi = bf16_rne(f);
            float hif = __uint_as_float(hi << 16);
            float lo = f - hif;
            h[j] = hi;
            l[j] = bf16_rne(lo);
        }
        int ng = n0 + nr;
        int pr = PERM ? permcol(ng) : ng;
        size_t idx = (size_t)pr * 1024 + k0 + tc * 4;
        uint2 ph, pl;
        ph.x = h[0] | (h[1] << 16); ph.y = h[2] | (h[3] << 16);
        pl.x = l[0] | (l[1] << 16); pl.y = l[2] | (l[3] << 16);
        *(uint2*)&Thi[idx] = ph;
        *(uint2*)&Tlo[idx] = pl;
    }
}

// ---------------------------------------------------------------------------
// Permute Wi columns: WiP[r][n] = Wi[r][orig(n)]
// ---------------------------------------------------------------------------
__global__ __launch_bounds__(256) void permute_wi(
    const float* __restrict__ Wi, float* __restrict__ WiP)
{
    __shared__ float l[256 * 17];
    int r = blockIdx.y, hb = blockIdx.x, tid = threadIdx.x;
    const float* src = Wi + (size_t)r * 16384;
    float* dst = WiP + (size_t)r * 16384;
#pragma unroll
    for (int kg = 0; kg < 16; ++kg) {
        int k = kg >> 2, g = kg & 3;
        l[tid * 17 + kg] = src[k * 4096 + g * 1024 + hb * 256 + tid];
    }
    __syncthreads();
#pragma unroll
    for (int it = 0; it < 16; ++it) {
        int j = it * 256 + tid;
        dst[hb * 4096 + j] = l[(j >> 4) * 17 + (j & 15)];
    }
}

// ---------------------------------------------------------------------------
// Init: bsum = bi + bh (plain and permuted)
// ---------------------------------------------------------------------------
__global__ __launch_bounds__(256) void init_state(
    float* __restrict__ bsum, float* __restrict__ bsumP,
    const float* __restrict__ bi, const float* __restrict__ bh)
{
    int i = blockIdx.x * 256 + threadIdx.x;   // 0..16383
    float v = bi[i] + bh[i];
    bsum[i] = v;
    bsumP[permcol(i)] = v;
}

// ---------------------------------------------------------------------------
// Transpose X [256][128] -> XT [128][256]
// ---------------------------------------------------------------------------
__global__ __launch_bounds__(256) void transpose_x(
    const int* __restrict__ X, int* __restrict__ XT)
{
    int t = blockIdx.x, b = threadIdx.x;
    XT[t * 256 + b] = X[b * 128 + t];
}

// ---------------------------------------------------------------------------
// Step 0: h == 0, c == 0 -> gates = bsum + Wi[X[b,0]], cell update inline.
// c4 layout: c4[(hx*256 + b)*4 ..] = float4 over k. h row-major split.
// ---------------------------------------------------------------------------
__global__ __launch_bounds__(256) void cell0(
    const float* __restrict__ bsum, const int* __restrict__ X,
    const float* __restrict__ Wi,
    float* __restrict__ c4, u16* __restrict__ Ohi, u16* __restrict__ Olo)
{
    int gid = blockIdx.x * 256 + threadIdx.x;   // 0..262143
    int b = gid & 255, hx = gid >> 8;
    int xr = X[b * 128];
    const float* wr = Wi + (size_t)xr * 16384;
    float best = -3.4e38f, csel = 0.0f;
    float cn[4];
#pragma unroll
    for (int k = 0; k < 4; ++k) {
        int base = k * 4096 + hx;
        float gi = bsum[base + 0]    + wr[base + 0];
        float gf = bsum[base + 1024] + wr[base + 1024];
        float gg = bsum[base + 2048] + wr[base + 2048];
        float go = bsum[base + 3072] + wr[base + 3072];
        float ig = sigf(gi);
        float fg = sigf(gf); (void)fg;           // c_old = 0
        float tg = tanhf(gg);
        cn[k] = ig * tg;
        if (go > best) { best = go; csel = cn[k]; }
    }
    float4 cv = {cn[0], cn[1], cn[2], cn[3]};
    *(float4*)&c4[((size_t)hx * 256 + b) * 4] = cv;
    float h = sigf(best) * tanhf(csel);
    u32 hi = bf16_rne(h);
    float hif = __uint_as_float(hi << 16);
    u32 lo = bf16_rne(h - hif);
    Ohi[(size_t)b * 1024 + hx] = (u16)hi;
    Olo[(size_t)b * 1024 + hx] = (u16)lo;
}

// ---------------------------------------------------------------------------
// Fused step: gates GEMM (bf16x3, permuted cols) + cell update.
// BM=128, BN=128, BK=32; 512 threads = 8 waves (2m x 4n), wave tile 64x32.
// grid 256 -> 1 block/CU.  [R1 schedule — best measured]
// R7: K-loop ported to v_mfma_f32_32x32x16_bf16 (17% fewer MFMA issue
// cycles, half the MFMA instruction count). Wave tile = two 32x32 m-tiles
// x K-slices s in {0,1}; 12 MFMAs + 12 ds_read_b128 per wave per kc.
// A/B frag: lane -> (row = lane&31, k = (lane>>5)*8 + j).
// C/D frag: col = lane&31, row = (reg&3) + 8*(reg>>2) + 4*(lane>>5).
// Granule index g = s*2 + (lane>>5) replaces the 16x16 'quad'; the same
// global-side rotation sg=(s+(row>>1))&3 / un-rotation (g-(row>>1))&3
// keeps frag reads at the bank minimum.
// Pipeline: 3 LDS staging buffers, depth-2 prefetch, counted vmcnt(4).
// Epilogue operands (XT, WiP gather, c4) hoisted under kc0 (R6).
// ---------------------------------------------------------------------------
__global__ __launch_bounds__(512, 2) void fused_step(
    const u16* __restrict__ Ahi, const u16* __restrict__ Alo,
    const u16* __restrict__ Bhi, const u16* __restrict__ Blo,
    const float* __restrict__ bsumP, const float* __restrict__ WiP,
    const int* __restrict__ XT, int t,
    float* __restrict__ c4, u16* __restrict__ Ohi, u16* __restrict__ Olo)
{
    constexpr int KD = 1024;
    // staging per buf (u16): Ahi [0,4096) Alo [4096,8192) Bhi [8192,12288) Blo [12288,16384)
    // 3 bufs x 32 KB = 96 KB; epilogue: 8 wave-private tiles 64x33 floats = 67584 B (reuse)
    __shared__ __align__(16) char smem[98304];
    u16* lds = (u16*)smem;
    float* tileb = (float*)smem;

    int bid = blockIdx.x;
    int xcd = bid & 7, rr = bid >> 3;           // rr 0..31
    int m0 = (rr & 1) * 128;
    int n0 = (((rr >> 1) * 8) + xcd) * 128;     // 0..16256
    int tid  = threadIdx.x;
    int lane = tid & 63;
    int wave = tid >> 6;                        // 0..7
    int wm = wave >> 2, wn = wave & 3;          // 2m x 4n
    int quad = lane >> 4, l15 = lane & 15;      // for epilogue-unchanged paths
    int l31 = lane & 31, hi32 = lane >> 5;

    // epilogue addressing (hoisted)
    int bg = m0 + wm * 64 + lane;
    int hxbase = (n0 + wn * 32) >> 4;

    // X row for this step: issued FIRST so the prologue vmcnt(4) drains it
    int xr = XT[t * 256 + bg];

    f32x16 acc[2] = {};                          // two 32x32 m-tiles

    int srow = tid >> 2, ss = tid & 3;
    int sg = (ss + (srow >> 1)) & 3;            // rotated k-segment (global side)
    auto stage = [&](int base, int kc) {
        int k0 = kc * 32;
        size_t ga = (size_t)(m0 + srow) * KD + k0 + sg * 8;
        size_t gb = (size_t)(n0 + srow) * KD + k0 + sg * 8;
        GLD_LDS(Ahi + ga, &lds[base + 0     + tid * 8]);
        GLD_LDS(Alo + ga, &lds[base + 4096  + tid * 8]);
        GLD_LDS(Bhi + gb, &lds[base + 8192  + tid * 8]);
        GLD_LDS(Blo + gb, &lds[base + 12288 + tid * 8]);
    };

    // frag read offsets (un-rotate the segment): phys = (g - (row>>1)) & 3
    // A: per (mt, s): row = wm*64 + mt*32 + l31, granule g = s*2 + hi32
    int aro[4], bro[2];
#pragma unroll
    for (int mt = 0; mt < 2; ++mt)
#pragma unroll
        for (int s = 0; s < 2; ++s) {
            int ar = wm * 64 + mt * 32 + l31;   // 0..127
            int g  = s * 2 + hi32;
            aro[mt * 2 + s] = ar * 32 + (((g - (ar >> 1)) & 3) * 8);
        }
#pragma unroll
    for (int s = 0; s < 2; ++s) {
        int br = wn * 32 + l31;                 // 0..127
        int g  = s * 2 + hi32;
        bro[s] = br * 32 + (((g - (br >> 1)) & 3) * 8);
    }

    constexpr int NK = KD / 32;
    // prologue: stage kc=0,1 into bufs 0,1; vmcnt(4) drains XT + buf 0
    stage(0, 0);
    stage(16384, 1);
    asm volatile("s_waitcnt vmcnt(4)" ::: "memory");
    __builtin_amdgcn_s_barrier();
    asm volatile("" ::: "memory");

    // issue the scattered epilogue gather NOW (xr already drained — no wait);
    // these 10 loads complete under kc0 and are drained by kc0's vmcnt(4).
    float4 wv[2][4];
    float4 cc[2];
#pragma unroll
    for (int u = 0; u < 2; ++u) {
        const float4* wipp = (const float4*)&WiP[(size_t)xr * 16384 + (hxbase + u) * 16];
#pragma unroll
        for (int k = 0; k < 4; ++k) wv[u][k] = wipp[k];
        cc[u] = *(const float4*)&c4[((size_t)(hxbase + u) * 256 + bg) * 4];
    }

    int basec = 0;                               // u16 base of buf kc%3
    for (int kc = 0; kc < NK; ++kc) {
        short8 ah[2][2], al[2][2], bh[2], bl[2];
#pragma unroll
        for (int mt = 0; mt < 2; ++mt)
#pragma unroll
            for (int s = 0; s < 2; ++s) {
                ah[mt][s] = *(const short8*)&lds[basec + 0    + aro[mt * 2 + s]];
                al[mt][s] = *(const short8*)&lds[basec + 4096 + aro[mt * 2 + s]];
            }
#pragma unroll
        for (int s = 0; s < 2; ++s) {
            bh[s] = *(const short8*)&lds[basec + 8192  + bro[s]];
            bl[s] = *(const short8*)&lds[basec + 12288 + bro[s]];
        }
        if (kc + 2 < NK) {
            int basen = basec + 32768;           // (kc+2)%3 buffer
            if (basen >= 49152) basen -= 49152;
            stage(basen, kc + 2);
        }
        // 12 MFMAs: per k-slice, terms hh, hl, lh; tiles interleaved for
        // dependency distance (acc[0]/acc[1] alternate).
#pragma unroll
        for (int s = 0; s < 2; ++s) {
            acc[0] = __builtin_amdgcn_mfma_f32_32x32x16_bf16(ah[0][s], bh[s], acc[0], 0, 0, 0);
            acc[1] = __builtin_amdgcn_mfma_f32_32x32x16_bf16(ah[1][s], bh[s], acc[1], 0, 0, 0);
            acc[0] = __builtin_amdgcn_mfma_f32_32x32x16_bf16(ah[0][s], bl[s], acc[0], 0, 0, 0);
            acc[1] = __builtin_amdgcn_mfma_f32_32x32x16_bf16(ah[1][s], bl[s], acc[1], 0, 0, 0);
            acc[0] = __builtin_amdgcn_mfma_f32_32x32x16_bf16(al[0][s], bh[s], acc[0], 0, 0, 0);
            acc[1] = __builtin_amdgcn_mfma_f32_32x32x16_bf16(al[1][s], bh[s], acc[1], 0, 0, 0);
        }

        // counted wait: buf (kc+1)%3's loads (issued at kc-1) must be complete;
        // the 4 loads just issued for kc+2 may remain in flight.
        if (kc + 2 < NK) {
            asm volatile("s_waitcnt vmcnt(4)" ::: "memory");
        } else {
            asm volatile("s_waitcnt vmcnt(0)" ::: "memory");
        }
        __builtin_amdgcn_s_barrier();
        asm volatile("" ::: "memory");

        basec += 16384;
        if (basec >= 49152) basec = 0;
    }

    __syncthreads();   // staging region -> epilogue tile reuse (queues already drained)

    // Phase 1: raw acc -> wave-private tile [64][33]
    // 32x32 C layout: col = lane&31, row = (reg&3) + 8*(reg>>2) + 4*(lane>>5)
    float* wt = tileb + wave * (64 * 33);
#pragma unroll
    for (int mt = 0; mt < 2; ++mt)
#pragma unroll
        for (int reg = 0; reg < 16; ++reg) {
            int rl = mt * 32 + (reg & 3) + 8 * (reg >> 2) + 4 * hi32;   // 0..63
            int cl = l31;                                               // 0..31
            wt[rl * 33 + cl] = acc[mt][reg];
        }

    // Phase 2: per-lane cell update — all operands already in registers.
#pragma unroll
    for (int u = 0; u < 2; ++u) {
        int hxg = hxbase + u;
        const float* g16 = &wt[lane * 33 + u * 16];
        const float4* bsp = (const float4*)&bsumP[hxg * 16];
        float* cp = &c4[((size_t)hxg * 256 + bg) * 4];
        float ca[4] = {cc[u].x, cc[u].y, cc[u].z, cc[u].w};
        float best = -3.4e38f, csel = 0.0f;
        float cn[4];
#pragma unroll
        for (int k = 0; k < 4; ++k) {
            float4 wvk = wv[u][k];
            float4 bv = bsp[k];
            float gi = (g16[k * 4 + 0] + bv.x) + wvk.x;
            float gf = (g16[k * 4 + 1] + bv.y) + wvk.y;
            float gg = (g16[k * 4 + 2] + bv.z) + wvk.z;
            float go = (g16[k * 4 + 3] + bv.w) + wvk.w;
            float ig = sigf(gi);
            float fg = sigf(gf);
            float tg = tanhf(gg);
            cn[k] = fg * ca[k] + ig * tg;
            if (go > best) { best = go; csel = cn[k]; }   // strict > = first max
        }
        float4 cv = {cn[0], cn[1], cn[2], cn[3]};
        *(float4*)cp = cv;
        float h = sigf(best) * tanhf(csel);
        u32 hi = bf16_rne(h);
        float hif = __uint_as_float(hi << 16);
        u32 lo = bf16_rne(h - hif);
        Ohi[(size_t)bg * 1024 + hxg] = (u16)hi;
        Olo[(size_t)bg * 1024 + hxg] = (u16)lo;
    }
}

// ---------------------------------------------------------------------------
// Logits GEMM (LDS structure): C[256][1024] = h @ Wl + bl. BM=128,BN=128, grid 16.
// ---------------------------------------------------------------------------
__global__ __launch_bounds__(256) void gemm_logits(
    const u16* __restrict__ Ahi, const u16* __restrict__ Alo,
    const u16* __restrict__ Bhi, const u16* __restrict__ Blo,
    float* __restrict__ C, const float* __restrict__ bias)
{
    constexpr int KD = 1024;
    __shared__ u16 lds[2][16384];
    int bid = blockIdx.x;
    int xcd = bid & 7, g = bid >> 3;
    int m0 = g * 128;
    int n0 = xcd * 128;
    int tid  = threadIdx.x;
    int lane = tid & 63;
    int wave = tid >> 6;
    int wm = wave >> 1, wn = wave & 1;
    int quad = lane >> 4, l15 = lane & 15;

    f32x4 acc[4][4] = {};

    auto stage = [&](int buf, int kc) {
        int k0 = kc * 32;
#pragma unroll
        for (int j = 0; j < 2; ++j) {
            int seg = j * 256 + tid;
            int row = seg >> 2, s = seg & 3;
            size_t ga = (size_t)(m0 + row) * KD + k0 + s * 8;
            GLD_LDS(Ahi + ga, &lds[buf][0    + seg * 8]);
            GLD_LDS(Alo + ga, &lds[buf][4096 + seg * 8]);
            size_t gb = (size_t)(n0 + row) * KD + k0 + s * 8;
            GLD_LDS(Bhi + gb, &lds[buf][8192  + seg * 8]);
            GLD_LDS(Blo + gb, &lds[buf][12288 + seg * 8]);
        }
    };

    stage(0, 0);
    constexpr int NK = KD / 32;
    for (int kc = 0; kc < NK; ++kc) {
        __syncthreads();
        if (kc + 1 < NK) stage((kc + 1) & 1, kc + 1);
        int buf = kc & 1;
        short8 afh[4], afl[4], bfh[4], bfl[4];
#pragma unroll
        for (int i = 0; i < 4; ++i) {
            int ar = wm * 64 + i * 16 + l15;
            afh[i] = *(const short8*)&lds[buf][0    + ar * 32 + quad * 8];
            afl[i] = *(const short8*)&lds[buf][4096 + ar * 32 + quad * 8];
            int br = wn * 64 + i * 16 + l15;
            bfh[i] = *(const short8*)&lds[buf][8192  + br * 32 + quad * 8];
            bfl[i] = *(const short8*)&lds[buf][12288 + br * 32 + quad * 8];
        }
#pragma unroll
        for (int mi = 0; mi < 4; ++mi)
#pragma unroll
            for (int ni = 0; ni < 4; ++ni)
                acc[mi][ni] = __builtin_amdgcn_mfma_f32_16x16x32_bf16(afh[mi], bfh[ni], acc[mi][ni], 0, 0, 0);
#pragma unroll
        for (int mi = 0; mi < 4; ++mi)
#pragma unroll
            for (int ni = 0; ni < 4; ++ni)
                acc[mi][ni] = __builtin_amdgcn_mfma_f32_16x16x32_bf16(afh[mi], bfl[ni], acc[mi][ni], 0, 0, 0);
#pragma unroll
        for (int mi = 0; mi < 4; ++mi)
#pragma unroll
            for (int ni = 0; ni < 4; ++ni)
                acc[mi][ni] = __builtin_amdgcn_mfma_f32_16x16x32_bf16(afl[mi], bfh[ni], acc[mi][ni], 0, 0, 0);
    }

#pragma unroll
    for (int mi = 0; mi < 4; ++mi) {
        int rbase = m0 + wm * 64 + mi * 16 + quad * 4;
#pragma unroll
        for (int ni = 0; ni < 4; ++ni) {
            int col = n0 + wn * 64 + ni * 16 + l15;
            float bv = bias[col];
#pragma unroll
            for (int r = 0; r < 4; ++r)
                C[(size_t)(rbase + r) * 1024 + col] = acc[mi][ni][r] + bv;
        }
    }
}

// ---------------------------------------------------------------------------
// Row-wise log_softmax in place over [256][1024]
// ---------------------------------------------------------------------------
__global__ __launch_bounds__(256) void logsoftmax_k(float* __restrict__ io)
{
    int b = blockIdx.x;
    float* row = io + (size_t)b * 1024;
    int tid = threadIdx.x;
    float x0 = row[tid], x1 = row[tid + 256], x2 = row[tid + 512], x3 = row[tid + 768];
    float m = fmaxf(fmaxf(x0, x1), fmaxf(x2, x3));
#pragma unroll
    for (int off = 32; off > 0; off >>= 1) m = fmaxf(m, __shfl_down(m, off, 64));
    __shared__ float sm[4], ss[4];
    if ((tid & 63) == 0) sm[tid >> 6] = m;
    __syncthreads();
    float M = fmaxf(fmaxf(sm[0], sm[1]), fmaxf(sm[2], sm[3]));
    float s = expf(x0 - M) + expf(x1 - M) + expf(x2 - M) + expf(x3 - M);
#pragma unroll
    for (int off = 32; off > 0; off >>= 1) s += __shfl_down(s, off, 64);
    if ((tid & 63) == 0) ss[tid >> 6] = s;
    __syncthreads();
    float L = M + logf(ss[0] + ss[1] + ss[2] + ss[3]);
    row[tid] = x0 - L; row[tid + 256] = x1 - L; row[tid + 512] = x2 - L; row[tid + 768] = x3 - L;
}

// ---------------------------------------------------------------------------
extern "C" void kernel_launch(void* const* d_in, const int* in_sizes, int n_in,
                              void* d_out, int out_size, void* d_ws, size_t ws_size,
                              hipStream_t stream)
{
    const int*   X  = (const int*)d_in[0];
    const float* Wi = (const float*)d_in[1];
    const float* bi = (const float*)d_in[2];
    const float* Wh = (const float*)d_in[3];
    const float* bh = (const float*)d_in[4];
    const float* Wl = (const float*)d_in[5];
    const float* bl = (const float*)d_in[6];
    float* out = (float*)d_out;

    char* p = (char*)d_ws;
    auto alloc = [&](size_t bytes) {
        char* r = p;
        p += (bytes + 255) & ~(size_t)255;
        return r;
    };
    u16*   WhTh = (u16*)alloc((size_t)16384 * 1024 * 2);
    u16*   WhTl = (u16*)alloc((size_t)16384 * 1024 * 2);
    u16*   WlTh = (u16*)alloc((size_t)1024 * 1024 * 2);
    u16*   WlTl = (u16*)alloc((size_t)1024 * 1024 * 2);
    float* WiP  = (float*)alloc((size_t)1024 * 16384 * 4);
    float* c4   = (float*)alloc((size_t)256 * 1024 * 4 * 4);
    u16*   h0h  = (u16*)alloc((size_t)262144 * 2);
    u16*   h0l  = (u16*)alloc((size_t)262144 * 2);
    u16*   h1h  = (u16*)alloc((size_t)262144 * 2);
    u16*   h1l  = (u16*)alloc((size_t)262144 * 2);
    float* bsum  = (float*)alloc((size_t)16384 * 4);
    float* bsumP = (float*)alloc((size_t)16384 * 4);
    int*   XT    = (int*)alloc((size_t)128 * 256 * 4);

    transpose_split<true><<<dim3(256, 16), 256, 0, stream>>>(Wh, WhTh, WhTl, 16384);
    transpose_split<false><<<dim3(16, 16), 256, 0, stream>>>(Wl, WlTh, WlTl, 1024);
    permute_wi<<<dim3(4, 1024), 256, 0, stream>>>(Wi, WiP);
    init_state<<<64, 256, 0, stream>>>(bsum, bsumP, bi, bh);
    transpose_x<<<128, 256, 0, stream>>>(X, XT);

    // Step 0 (h=0, c=0): writes h buffer 1
    cell0<<<1024, 256, 0, stream>>>(bsum, X, Wi, c4, h1h, h1l);

    for (int t = 1; t < 128; ++t) {
        const u16* ih = (t & 1) ? h1h : h0h;
        const u16* il = (t & 1) ? h1l : h0l;
        u16* oh = (t & 1) ? h0h : h1h;
        u16* ol = (t & 1) ? h0l : h1l;
        fused_step<<<256, 512, 0, stream>>>(ih, il, WhTh, WhTl, bsumP, WiP, XT, t, c4, oh, ol);
    }

    // t=127 wrote buffer 0
    gemm_logits<<<16, 256, 0, stream>>>(h0h, h0l, WlTh, WlTl, out, bl);
    logsoftmax_k<<<256, 256, 0, stream>>>(out);
}

// Round 8
// 4339.607 us; speedup vs baseline: 1.0920x; 1.0920x over previous
//
#include <hip/hip_runtime.h>
#include <hip/hip_bf16.h>

typedef unsigned short u16;
typedef unsigned int u32;
typedef __attribute__((ext_vector_type(8))) short short8;
typedef __attribute__((ext_vector_type(4))) float f32x4;

#define GLD_LDS(gptr, lptr) \
    __builtin_amdgcn_global_load_lds((const __attribute__((address_space(1))) void*)(gptr), \
                                     (__attribute__((address_space(3))) void*)(lptr), 16, 0, 0)

__device__ __forceinline__ u32 bf16_rne(float f) {
    u32 u = __float_as_uint(f);
    return (u + 0x7FFFu + ((u >> 16) & 1u)) >> 16;
}

// column permutation: orig col c = k*4096 + g*1024 + hx  ->  n = hx*16 + k*4 + g
__device__ __forceinline__ int permcol(int c) {
    return (c & 1023) * 16 + ((c >> 12) & 3) * 4 + ((c >> 10) & 3);
}

__device__ __forceinline__ float sigf(float x) { return 1.0f / (1.0f + expf(-x)); }

// ---------------------------------------------------------------------------
// Transpose + split fp32 [1024][N] -> bf16 hi/lo [N'][1024] row-major
// ---------------------------------------------------------------------------
template <bool PERM>
__global__ __launch_bounds__(256) void transpose_split(
    const float* __restrict__ W, u16* __restrict__ Thi, u16* __restrict__ Tlo, int N)
{
    __shared__ float tile[64][65];
    int n0 = blockIdx.x * 64;
    int k0 = blockIdx.y * 64;
    int tid = threadIdx.x;
    int tr = tid >> 4;      // 0..15
    int tc = tid & 15;      // 0..15
#pragma unroll
    for (int it = 0; it < 4; ++it) {
        int kr = it * 16 + tr;
        const float4* src = (const float4*)&W[(size_t)(k0 + kr) * N + n0 + tc * 4];
        float4 v = *src;
        tile[kr][tc * 4 + 0] = v.x;
        tile[kr][tc * 4 + 1] = v.y;
        tile[kr][tc * 4 + 2] = v.z;
        tile[kr][tc * 4 + 3] = v.w;
    }
    __syncthreads();
#pragma unroll
    for (int it = 0; it < 4; ++it) {
        int nr = it * 16 + tr;
        u32 h[4], l[4];
#pragma unroll
        for (int j = 0; j < 4; ++j) {
            float f = tile[tc * 4 + j][nr];
            u32 hi = bf16_rne(f);
            float hif = __uint_as_float(hi << 16);
            float lo = f - hif;
            h[j] = hi;
            l[j] = bf16_rne(lo);
        }
        int ng = n0 + nr;
        int pr = PERM ? permcol(ng) : ng;
        size_t idx = (size_t)pr * 1024 + k0 + tc * 4;
        uint2 ph, pl;
        ph.x = h[0] | (h[1] << 16); ph.y = h[2] | (h[3] << 16);
        pl.x = l[0] | (l[1] << 16); pl.y = l[2] | (l[3] << 16);
        *(uint2*)&Thi[idx] = ph;
        *(uint2*)&Tlo[idx] = pl;
    }
}

// ---------------------------------------------------------------------------
// Permute Wi columns: WiP[r][n] = Wi[r][orig(n)]
// ---------------------------------------------------------------------------
__global__ __launch_bounds__(256) void permute_wi(
    const float* __restrict__ Wi, float* __restrict__ WiP)
{
    __shared__ float l[256 * 17];
    int r = blockIdx.y, hb = blockIdx.x, tid = threadIdx.x;
    const float* src = Wi + (size_t)r * 16384;
    float* dst = WiP + (size_t)r * 16384;
#pragma unroll
    for (int kg = 0; kg < 16; ++kg) {
        int k = kg >> 2, g = kg & 3;
        l[tid * 17 + kg] = src[k * 4096 + g * 1024 + hb * 256 + tid];
    }
    __syncthreads();
#pragma unroll
    for (int it = 0; it < 16; ++it) {
        int j = it * 256 + tid;
        dst[hb * 4096 + j] = l[(j >> 4) * 17 + (j & 15)];
    }
}

// ---------------------------------------------------------------------------
// Init: bsum = bi + bh (plain and permuted)
// ---------------------------------------------------------------------------
__global__ __launch_bounds__(256) void init_state(
    float* __restrict__ bsum, float* __restrict__ bsumP,
    const float* __restrict__ bi, const float* __restrict__ bh)
{
    int i = blockIdx.x * 256 + threadIdx.x;   // 0..16383
    float v = bi[i] + bh[i];
    bsum[i] = v;
    bsumP[permcol(i)] = v;
}

// ---------------------------------------------------------------------------
// Transpose X [256][128] -> XT [128][256]
// ---------------------------------------------------------------------------
__global__ __launch_bounds__(256) void transpose_x(
    const int* __restrict__ X, int* __restrict__ XT)
{
    int t = blockIdx.x, b = threadIdx.x;
    XT[t * 256 + b] = X[b * 128 + t];
}

// ---------------------------------------------------------------------------
// Step 0: h == 0, c == 0 -> gates = bsum + Wi[X[b,0]], cell update inline.
// c4 layout: c4[(hx*256 + b)*4 ..] = float4 over k. h row-major split.
// ---------------------------------------------------------------------------
__global__ __launch_bounds__(256) void cell0(
    const float* __restrict__ bsum, const int* __restrict__ X,
    const float* __restrict__ Wi,
    float* __restrict__ c4, u16* __restrict__ Ohi, u16* __restrict__ Olo)
{
    int gid = blockIdx.x * 256 + threadIdx.x;   // 0..262143
    int b = gid & 255, hx = gid >> 8;
    int xr = X[b * 128];
    const float* wr = Wi + (size_t)xr * 16384;
    float best = -3.4e38f, csel = 0.0f;
    float cn[4];
#pragma unroll
    for (int k = 0; k < 4; ++k) {
        int base = k * 4096 + hx;
        float gi = bsum[base + 0]    + wr[base + 0];
        float gf = bsum[base + 1024] + wr[base + 1024];
        float gg = bsum[base + 2048] + wr[base + 2048];
        float go = bsum[base + 3072] + wr[base + 3072];
        float ig = sigf(gi);
        float fg = sigf(gf); (void)fg;           // c_old = 0
        float tg = tanhf(gg);
        cn[k] = ig * tg;
        if (go > best) { best = go; csel = cn[k]; }
    }
    float4 cv = {cn[0], cn[1], cn[2], cn[3]};
    *(float4*)&c4[((size_t)hx * 256 + b) * 4] = cv;
    float h = sigf(best) * tanhf(csel);
    u32 hi = bf16_rne(h);
    float hif = __uint_as_float(hi << 16);
    u32 lo = bf16_rne(h - hif);
    Ohi[(size_t)b * 1024 + hx] = (u16)hi;
    Olo[(size_t)b * 1024 + hx] = (u16)lo;
}

// ---------------------------------------------------------------------------
// Fused step: gates GEMM (bf16x3, permuted cols) + cell update.
// BM=128, BN=128, BK=32; 512 threads = 8 waves (2m x 4n), wave tile 64x32
// (acc 4x2). grid 256 -> 1 block/CU.  [R6 schedule — best measured 4315 µs]
// R8: depth-3 staging pipeline — 4 LDS buffers (128 KB), stage kc+3 each
// iteration. Gives each load burst ~2 kc bodies of slack before its vmcnt
// (cross-XCD h fetches are mandatory L2 misses ~900+ cyc with jitter; the
// depth-2 pipeline gave only ~1 body). vmcnt schedule (queue also holds the
// 10 hoisted gather loads early on): prologue vmcnt(8); steady vmcnt(8);
// kc==NK-3 vmcnt(4); kc>=NK-2 vmcnt(0). WAR: buf (kc+3)&3 was consumed at
// kc-1 whose end-barrier precedes this overwrite.
// 16x16x32 MFMA (R7's 32x32 port regressed: 24x bank conflicts).
// Epilogue operands (XT, WiP gather, c4) hoisted under kc0 (R6).
// Bank-conflict-free frag reads via k-segment rotation sg=(s+(row>>1))&3
// applied on the GLOBAL side (LDS dest stays lane-ordered for global_load_lds).
// ---------------------------------------------------------------------------
__global__ __launch_bounds__(512, 2) void fused_step(
    const u16* __restrict__ Ahi, const u16* __restrict__ Alo,
    const u16* __restrict__ Bhi, const u16* __restrict__ Blo,
    const float* __restrict__ bsumP, const float* __restrict__ WiP,
    const int* __restrict__ XT, int t,
    float* __restrict__ c4, u16* __restrict__ Ohi, u16* __restrict__ Olo)
{
    constexpr int KD = 1024;
    // staging per buf (u16): Ahi [0,4096) Alo [4096,8192) Bhi [8192,12288) Blo [12288,16384)
    // 4 bufs x 32 KB = 128 KB; epilogue: 8 wave-private tiles 64x33 floats = 67584 B (reuse)
    __shared__ __align__(16) char smem[131072];
    u16* lds = (u16*)smem;
    float* tileb = (float*)smem;

    int bid = blockIdx.x;
    int xcd = bid & 7, rr = bid >> 3;           // rr 0..31
    int m0 = (rr & 1) * 128;
    int n0 = (((rr >> 1) * 8) + xcd) * 128;     // 0..16256
    int tid  = threadIdx.x;
    int lane = tid & 63;
    int wave = tid >> 6;                        // 0..7
    int wm = wave >> 2, wn = wave & 3;          // 2m x 4n
    int quad = lane >> 4, l15 = lane & 15;

    // epilogue addressing (hoisted)
    int bg = m0 + wm * 64 + lane;
    int hxbase = (n0 + wn * 32) >> 4;

    // X row for this step: issued FIRST so the prologue vmcnt(8) drains it
    int xr = XT[t * 256 + bg];

    f32x4 acc[4][2] = {};

    int srow = tid >> 2, ss = tid & 3;
    int sg = (ss + (srow >> 1)) & 3;            // rotated k-segment (global side)
    auto stage = [&](int base, int kc) {
        int k0 = kc * 32;
        size_t ga = (size_t)(m0 + srow) * KD + k0 + sg * 8;
        size_t gb = (size_t)(n0 + srow) * KD + k0 + sg * 8;
        GLD_LDS(Ahi + ga, &lds[base + 0     + tid * 8]);
        GLD_LDS(Alo + ga, &lds[base + 4096  + tid * 8]);
        GLD_LDS(Bhi + gb, &lds[base + 8192  + tid * 8]);
        GLD_LDS(Blo + gb, &lds[base + 12288 + tid * 8]);
    };

    // frag read offsets (un-rotate the segment): phys = (quad - (row>>1)) & 3
    int aro[4], bro[2];
#pragma unroll
    for (int mi = 0; mi < 4; ++mi) {
        int ar = wm * 64 + mi * 16 + l15;       // 0..127
        aro[mi] = ar * 32 + (((quad - (ar >> 1)) & 3) * 8);
    }
#pragma unroll
    for (int ni = 0; ni < 2; ++ni) {
        int br = wn * 32 + ni * 16 + l15;       // 0..127
        bro[ni] = br * 32 + (((quad - (br >> 1)) & 3) * 8);
    }

    constexpr int NK = KD / 32;
    // prologue: stage kc=0,1,2 into bufs 0,1,2; vmcnt(8) drains XT + buf 0
    stage(0, 0);
    stage(16384, 1);
    stage(32768, 2);
    asm volatile("s_waitcnt vmcnt(8)" ::: "memory");
    __builtin_amdgcn_s_barrier();
    asm volatile("" ::: "memory");

    // issue the scattered epilogue gather NOW (xr already drained — no wait);
    // these 10 loads complete under kc0/kc1 and are forced by the early
    // conservative vmcnt(8)s.
    float4 wv[2][4];
    float4 cc[2];
#pragma unroll
    for (int u = 0; u < 2; ++u) {
        const float4* wipp = (const float4*)&WiP[(size_t)xr * 16384 + (hxbase + u) * 16];
#pragma unroll
        for (int k = 0; k < 4; ++k) wv[u][k] = wipp[k];
        cc[u] = *(const float4*)&c4[((size_t)(hxbase + u) * 256 + bg) * 4];
    }

    for (int kc = 0; kc < NK; ++kc) {
        int basec = (kc & 3) * 16384;            // u16 base of buf kc%4
        short8 afh[4], afl[4], bfh[2], bfl[2];
#pragma unroll
        for (int mi = 0; mi < 4; ++mi) {
            afh[mi] = *(const short8*)&lds[basec + 0    + aro[mi]];
            afl[mi] = *(const short8*)&lds[basec + 4096 + aro[mi]];
        }
#pragma unroll
        for (int ni = 0; ni < 2; ++ni) {
            bfh[ni] = *(const short8*)&lds[basec + 8192  + bro[ni]];
            bfl[ni] = *(const short8*)&lds[basec + 12288 + bro[ni]];
        }
        if (kc + 3 < NK) {
            stage(((kc + 3) & 3) * 16384, kc + 3);
        }
        // term-major: 8 independent MFMAs per burst; per-acc order hh, hl, lh
#pragma unroll
        for (int mi = 0; mi < 4; ++mi)
#pragma unroll
            for (int ni = 0; ni < 2; ++ni)
                acc[mi][ni] = __builtin_amdgcn_mfma_f32_16x16x32_bf16(afh[mi], bfh[ni], acc[mi][ni], 0, 0, 0);
#pragma unroll
        for (int mi = 0; mi < 4; ++mi)
#pragma unroll
            for (int ni = 0; ni < 2; ++ni)
                acc[mi][ni] = __builtin_amdgcn_mfma_f32_16x16x32_bf16(afh[mi], bfl[ni], acc[mi][ni], 0, 0, 0);
#pragma unroll
        for (int mi = 0; mi < 4; ++mi)
#pragma unroll
            for (int ni = 0; ni < 2; ++ni)
                acc[mi][ni] = __builtin_amdgcn_mfma_f32_16x16x32_bf16(afl[mi], bfh[ni], acc[mi][ni], 0, 0, 0);

        // counted wait: buf (kc+1)&3 (issued at kc-2) must be complete; the
        // bufs for kc+2 and kc+3 (8 loads) may remain in flight.
        if (kc + 4 <= NK) {          // kc <= NK-4: two staged bufs ahead
            asm volatile("s_waitcnt vmcnt(8)" ::: "memory");
        } else if (kc + 3 == NK) {   // kc == NK-3: one staged buf ahead
            asm volatile("s_waitcnt vmcnt(4)" ::: "memory");
        } else {                     // kc >= NK-2: drain
            asm volatile("s_waitcnt vmcnt(0)" ::: "memory");
        }
        __builtin_amdgcn_s_barrier();
        asm volatile("" ::: "memory");
    }

    __syncthreads();   // staging region -> epilogue tile reuse (queues already drained)

    // Phase 1: raw acc -> wave-private tile [64][33]
    float* wt = tileb + wave * (64 * 33);
#pragma unroll
    for (int mi = 0; mi < 4; ++mi)
#pragma unroll
        for (int ni = 0; ni < 2; ++ni)
#pragma unroll
            for (int r = 0; r < 4; ++r) {
                int rl = mi * 16 + quad * 4 + r;    // 0..63
                int cl = ni * 16 + l15;             // 0..31
                wt[rl * 33 + cl] = acc[mi][ni][r];
            }

    // Phase 2: per-lane cell update — all operands already in registers.
#pragma unroll
    for (int u = 0; u < 2; ++u) {
        int hxg = hxbase + u;
        const float* g16 = &wt[lane * 33 + u * 16];
        const float4* bsp = (const float4*)&bsumP[hxg * 16];
        float* cp = &c4[((size_t)hxg * 256 + bg) * 4];
        float ca[4] = {cc[u].x, cc[u].y, cc[u].z, cc[u].w};
        float best = -3.4e38f, csel = 0.0f;
        float cn[4];
#pragma unroll
        for (int k = 0; k < 4; ++k) {
            float4 wvk = wv[u][k];
            float4 bv = bsp[k];
            float gi = (g16[k * 4 + 0] + bv.x) + wvk.x;
            float gf = (g16[k * 4 + 1] + bv.y) + wvk.y;
            float gg = (g16[k * 4 + 2] + bv.z) + wvk.z;
            float go = (g16[k * 4 + 3] + bv.w) + wvk.w;
            float ig = sigf(gi);
            float fg = sigf(gf);
            float tg = tanhf(gg);
            cn[k] = fg * ca[k] + ig * tg;
            if (go > best) { best = go; csel = cn[k]; }   // strict > = first max
        }
        float4 cv = {cn[0], cn[1], cn[2], cn[3]};
        *(float4*)cp = cv;
        float h = sigf(best) * tanhf(csel);
        u32 hi = bf16_rne(h);
        float hif = __uint_as_float(hi << 16);
        u32 lo = bf16_rne(h - hif);
        Ohi[(size_t)bg * 1024 + hxg] = (u16)hi;
        Olo[(size_t)bg * 1024 + hxg] = (u16)lo;
    }
}

// ---------------------------------------------------------------------------
// Logits GEMM (LDS structure): C[256][1024] = h @ Wl + bl. BM=128,BN=128, grid 16.
// ---------------------------------------------------------------------------
__global__ __launch_bounds__(256) void gemm_logits(
    const u16* __restrict__ Ahi, const u16* __restrict__ Alo,
    const u16* __restrict__ Bhi, const u16* __restrict__ Blo,
    float* __restrict__ C, const float* __restrict__ bias)
{
    constexpr int KD = 1024;
    __shared__ u16 lds[2][16384];
    int bid = blockIdx.x;
    int xcd = bid & 7, g = bid >> 3;
    int m0 = g * 128;
    int n0 = xcd * 128;
    int tid  = threadIdx.x;
    int lane = tid & 63;
    int wave = tid >> 6;
    int wm = wave >> 1, wn = wave & 1;
    int quad = lane >> 4, l15 = lane & 15;

    f32x4 acc[4][4] = {};

    auto stage = [&](int buf, int kc) {
        int k0 = kc * 32;
#pragma unroll
        for (int j = 0; j < 2; ++j) {
            int seg = j * 256 + tid;
            int row = seg >> 2, s = seg & 3;
            size_t ga = (size_t)(m0 + row) * KD + k0 + s * 8;
            GLD_LDS(Ahi + ga, &lds[buf][0    + seg * 8]);
            GLD_LDS(Alo + ga, &lds[buf][4096 + seg * 8]);
            size_t gb = (size_t)(n0 + row) * KD + k0 + s * 8;
            GLD_LDS(Bhi + gb, &lds[buf][8192  + seg * 8]);
            GLD_LDS(Blo + gb, &lds[buf][12288 + seg * 8]);
        }
    };

    stage(0, 0);
    constexpr int NK = KD / 32;
    for (int kc = 0; kc < NK; ++kc) {
        __syncthreads();
        if (kc + 1 < NK) stage((kc + 1) & 1, kc + 1);
        int buf = kc & 1;
        short8 afh[4], afl[4], bfh[4], bfl[4];
#pragma unroll
        for (int i = 0; i < 4; ++i) {
            int ar = wm * 64 + i * 16 + l15;
            afh[i] = *(const short8*)&lds[buf][0    + ar * 32 + quad * 8];
            afl[i] = *(const short8*)&lds[buf][4096 + ar * 32 + quad * 8];
            int br = wn * 64 + i * 16 + l15;
            bfh[i] = *(const short8*)&lds[buf][8192  + br * 32 + quad * 8];
            bfl[i] = *(const short8*)&lds[buf][12288 + br * 32 + quad * 8];
        }
#pragma unroll
        for (int mi = 0; mi < 4; ++mi)
#pragma unroll
            for (int ni = 0; ni < 4; ++ni)
                acc[mi][ni] = __builtin_amdgcn_mfma_f32_16x16x32_bf16(afh[mi], bfh[ni], acc[mi][ni], 0, 0, 0);
#pragma unroll
        for (int mi = 0; mi < 4; ++mi)
#pragma unroll
            for (int ni = 0; ni < 4; ++ni)
                acc[mi][ni] = __builtin_amdgcn_mfma_f32_16x16x32_bf16(afh[mi], bfl[ni], acc[mi][ni], 0, 0, 0);
#pragma unroll
        for (int mi = 0; mi < 4; ++mi)
#pragma unroll
            for (int ni = 0; ni < 4; ++ni)
                acc[mi][ni] = __builtin_amdgcn_mfma_f32_16x16x32_bf16(afl[mi], bfh[ni], acc[mi][ni], 0, 0, 0);
    }

#pragma unroll
    for (int mi = 0; mi < 4; ++mi) {
        int rbase = m0 + wm * 64 + mi * 16 + quad * 4;
#pragma unroll
        for (int ni = 0; ni < 4; ++ni) {
            int col = n0 + wn * 64 + ni * 16 + l15;
            float bv = bias[col];
#pragma unroll
            for (int r = 0; r < 4; ++r)
                C[(size_t)(rbase + r) * 1024 + col] = acc[mi][ni][r] + bv;
        }
    }
}

// ---------------------------------------------------------------------------
// Row-wise log_softmax in place over [256][1024]
// ---------------------------------------------------------------------------
__global__ __launch_bounds__(256) void logsoftmax_k(float* __restrict__ io)
{
    int b = blockIdx.x;
    float* row = io + (size_t)b * 1024;
    int tid = threadIdx.x;
    float x0 = row[tid], x1 = row[tid + 256], x2 = row[tid + 512], x3 = row[tid + 768];
    float m = fmaxf(fmaxf(x0, x1), fmaxf(x2, x3));
#pragma unroll
    for (int off = 32; off > 0; off >>= 1) m = fmaxf(m, __shfl_down(m, off, 64));
    __shared__ float sm[4], ss[4];
    if ((tid & 63) == 0) sm[tid >> 6] = m;
    __syncthreads();
    float M = fmaxf(fmaxf(sm[0], sm[1]), fmaxf(sm[2], sm[3]));
    float s = expf(x0 - M) + expf(x1 - M) + expf(x2 - M) + expf(x3 - M);
#pragma unroll
    for (int off = 32; off > 0; off >>= 1) s += __shfl_down(s, off, 64);
    if ((tid & 63) == 0) ss[tid >> 6] = s;
    __syncthreads();
    float L = M + logf(ss[0] + ss[1] + ss[2] + ss[3]);
    row[tid] = x0 - L; row[tid + 256] = x1 - L; row[tid + 512] = x2 - L; row[tid + 768] = x3 - L;
}

// ---------------------------------------------------------------------------
extern "C" void kernel_launch(void* const* d_in, const int* in_sizes, int n_in,
                              void* d_out, int out_size, void* d_ws, size_t ws_size,
                              hipStream_t stream)
{
    const int*   X  = (const int*)d_in[0];
    const float* Wi = (const float*)d_in[1];
    const float* bi = (const float*)d_in[2];
    const float* Wh = (const float*)d_in[3];
    const float* bh = (const float*)d_in[4];
    const float* Wl = (const float*)d_in[5];
    const float* bl = (const float*)d_in[6];
    float* out = (float*)d_out;

    char* p = (char*)d_ws;
    auto alloc = [&](size_t bytes) {
        char* r = p;
        p += (bytes + 255) & ~(size_t)255;
        return r;
    };
    u16*   WhTh = (u16*)alloc((size_t)16384 * 1024 * 2);
    u16*   WhTl = (u16*)alloc((size_t)16384 * 1024 * 2);
    u16*   WlTh = (u16*)alloc((size_t)1024 * 1024 * 2);
    u16*   WlTl = (u16*)alloc((size_t)1024 * 1024 * 2);
    float* WiP  = (float*)alloc((size_t)1024 * 16384 * 4);
    float* c4   = (float*)alloc((size_t)256 * 1024 * 4 * 4);
    u16*   h0h  = (u16*)alloc((size_t)262144 * 2);
    u16*   h0l  = (u16*)alloc((size_t)262144 * 2);
    u16*   h1h  = (u16*)alloc((size_t)262144 * 2);
    u16*   h1l  = (u16*)alloc((size_t)262144 * 2);
    float* bsum  = (float*)alloc((size_t)16384 * 4);
    float* bsumP = (float*)alloc((size_t)16384 * 4);
    int*   XT    = (int*)alloc((size_t)128 * 256 * 4);

    transpose_split<true><<<dim3(256, 16), 256, 0, stream>>>(Wh, WhTh, WhTl, 16384);
    transpose_split<false><<<dim3(16, 16), 256, 0, stream>>>(Wl, WlTh, WlTl, 1024);
    permute_wi<<<dim3(4, 1024), 256, 0, stream>>>(Wi, WiP);
    init_state<<<64, 256, 0, stream>>>(bsum, bsumP, bi, bh);
    transpose_x<<<128, 256, 0, stream>>>(X, XT);

    // Step 0 (h=0, c=0): writes h buffer 1
    cell0<<<1024, 256, 0, stream>>>(bsum, X, Wi, c4, h1h, h1l);

    for (int t = 1; t < 128; ++t) {
        const u16* ih = (t & 1) ? h1h : h0h;
        const u16* il = (t & 1) ? h1l : h0l;
        u16* oh = (t & 1) ? h0h : h1h;
        u16* ol = (t & 1) ? h0l : h1l;
        fused_step<<<256, 512, 0, stream>>>(ih, il, WhTh, WhTl, bsumP, WiP, XT, t, c4, oh, ol);
    }

    // t=127 wrote buffer 0
    gemm_logits<<<16, 256, 0, stream>>>(h0h, h0l, WlTh, WlTl, out, bl);
    logsoftmax_k<<<256, 256, 0, stream>>>(out);
}

// Round 9
// 3556.795 us; speedup vs baseline: 1.3323x; 1.2201x over previous
//
#include <hip/hip_runtime.h>
#include <hip/hip_bf16.h>

typedef unsigned short u16;
typedef unsigned int u32;
typedef __attribute__((ext_vector_type(8))) short short8;
typedef __attribute__((ext_vector_type(4))) float f32x4;

#define GLD_LDS(gptr, lptr) \
    __builtin_amdgcn_global_load_lds((const __attribute__((address_space(1))) void*)(gptr), \
                                     (__attribute__((address_space(3))) void*)(lptr), 16, 0, 0)

__device__ __forceinline__ u32 bf16_rne(float f) {
    u32 u = __float_as_uint(f);
    return (u + 0x7FFFu + ((u >> 16) & 1u)) >> 16;
}

// column permutation: orig col c = k*4096 + g*1024 + hx  ->  n = hx*16 + k*4 + g
__device__ __forceinline__ int permcol(int c) {
    return (c & 1023) * 16 + ((c >> 12) & 3) * 4 + ((c >> 10) & 3);
}

__device__ __forceinline__ float sigf(float x) { return 1.0f / (1.0f + expf(-x)); }

// ---------------------------------------------------------------------------
// Transpose + split fp32 [1024][N] -> bf16 hi/lo [N'][1024] row-major
// ---------------------------------------------------------------------------
template <bool PERM>
__global__ __launch_bounds__(256) void transpose_split(
    const float* __restrict__ W, u16* __restrict__ Thi, u16* __restrict__ Tlo, int N)
{
    __shared__ float tile[64][65];
    int n0 = blockIdx.x * 64;
    int k0 = blockIdx.y * 64;
    int tid = threadIdx.x;
    int tr = tid >> 4;      // 0..15
    int tc = tid & 15;      // 0..15
#pragma unroll
    for (int it = 0; it < 4; ++it) {
        int kr = it * 16 + tr;
        const float4* src = (const float4*)&W[(size_t)(k0 + kr) * N + n0 + tc * 4];
        float4 v = *src;
        tile[kr][tc * 4 + 0] = v.x;
        tile[kr][tc * 4 + 1] = v.y;
        tile[kr][tc * 4 + 2] = v.z;
        tile[kr][tc * 4 + 3] = v.w;
    }
    __syncthreads();
#pragma unroll
    for (int it = 0; it < 4; ++it) {
        int nr = it * 16 + tr;
        u32 h[4], l[4];
#pragma unroll
        for (int j = 0; j < 4; ++j) {
            float f = tile[tc * 4 + j][nr];
            u32 hi = bf16_rne(f);
            float hif = __uint_as_float(hi << 16);
            float lo = f - hif;
            h[j] = hi;
            l[j] = bf16_rne(lo);
        }
        int ng = n0 + nr;
        int pr = PERM ? permcol(ng) : ng;
        size_t idx = (size_t)pr * 1024 + k0 + tc * 4;
        uint2 ph, pl;
        ph.x = h[0] | (h[1] << 16); ph.y = h[2] | (h[3] << 16);
        pl.x = l[0] | (l[1] << 16); pl.y = l[2] | (l[3] << 16);
        *(uint2*)&Thi[idx] = ph;
        *(uint2*)&Tlo[idx] = pl;
    }
}

// ---------------------------------------------------------------------------
// Permute Wi columns: WiP[r][n] = Wi[r][orig(n)]
// ---------------------------------------------------------------------------
__global__ __launch_bounds__(256) void permute_wi(
    const float* __restrict__ Wi, float* __restrict__ WiP)
{
    __shared__ float l[256 * 17];
    int r = blockIdx.y, hb = blockIdx.x, tid = threadIdx.x;
    const float* src = Wi + (size_t)r * 16384;
    float* dst = WiP + (size_t)r * 16384;
#pragma unroll
    for (int kg = 0; kg < 16; ++kg) {
        int k = kg >> 2, g = kg & 3;
        l[tid * 17 + kg] = src[k * 4096 + g * 1024 + hb * 256 + tid];
    }
    __syncthreads();
#pragma unroll
    for (int it = 0; it < 16; ++it) {
        int j = it * 256 + tid;
        dst[hb * 4096 + j] = l[(j >> 4) * 17 + (j & 15)];
    }
}

// ---------------------------------------------------------------------------
// Init: bsum = bi + bh (plain and permuted)
// ---------------------------------------------------------------------------
__global__ __launch_bounds__(256) void init_state(
    float* __restrict__ bsum, float* __restrict__ bsumP,
    const float* __restrict__ bi, const float* __restrict__ bh)
{
    int i = blockIdx.x * 256 + threadIdx.x;   // 0..16383
    float v = bi[i] + bh[i];
    bsum[i] = v;
    bsumP[permcol(i)] = v;
}

// ---------------------------------------------------------------------------
// Transpose X [256][128] -> XT [128][256]
// ---------------------------------------------------------------------------
__global__ __launch_bounds__(256) void transpose_x(
    const int* __restrict__ X, int* __restrict__ XT)
{
    int t = blockIdx.x, b = threadIdx.x;
    XT[t * 256 + b] = X[b * 128 + t];
}

// ---------------------------------------------------------------------------
// Step 0: h == 0, c == 0 -> gates = bsum + Wi[X[b,0]], cell update inline.
// c4 layout: c4[(hx*256 + b)*4 ..] = float4 over k. h row-major split.
// ---------------------------------------------------------------------------
__global__ __launch_bounds__(256) void cell0(
    const float* __restrict__ bsum, const int* __restrict__ X,
    const float* __restrict__ Wi,
    float* __restrict__ c4, u16* __restrict__ Ohi, u16* __restrict__ Olo)
{
    int gid = blockIdx.x * 256 + threadIdx.x;   // 0..262143
    int b = gid & 255, hx = gid >> 8;
    int xr = X[b * 128];
    const float* wr = Wi + (size_t)xr * 16384;
    float best = -3.4e38f, csel = 0.0f;
    float cn[4];
#pragma unroll
    for (int k = 0; k < 4; ++k) {
        int base = k * 4096 + hx;
        float gi = bsum[base + 0]    + wr[base + 0];
        float gf = bsum[base + 1024] + wr[base + 1024];
        float gg = bsum[base + 2048] + wr[base + 2048];
        float go = bsum[base + 3072] + wr[base + 3072];
        float ig = sigf(gi);
        float fg = sigf(gf); (void)fg;           // c_old = 0
        float tg = tanhf(gg);
        cn[k] = ig * tg;
        if (go > best) { best = go; csel = cn[k]; }
    }
    float4 cv = {cn[0], cn[1], cn[2], cn[3]};
    *(float4*)&c4[((size_t)hx * 256 + b) * 4] = cv;
    float h = sigf(best) * tanhf(csel);
    u32 hi = bf16_rne(h);
    float hif = __uint_as_float(hi << 16);
    u32 lo = bf16_rne(h - hif);
    Ohi[(size_t)b * 1024 + hx] = (u16)hi;
    Olo[(size_t)b * 1024 + hx] = (u16)lo;
}

// ---------------------------------------------------------------------------
// Fused step: gates GEMM + cell update.
// BM=128, BN=128, BK=32; 512 threads = 8 waves (2m x 4n), wave tile 64x32
// (acc 4x2). grid 256 -> 1 block/CU.  [R6 schedule — best measured 4315 µs]
// R9: B-operand (Wh) in SINGLE bf16 — drop the Blo correction term.
// gates = (Ahi + Alo) @ Bhi : 2 MFMA terms (16/kc/wave, was 24), 10 ds_reads
// (was 12), 24 KB staged/kc (was 32). Equivalent to running the exact
// recurrence with |dWh|/|Wh| <= 2^-9 static weight perturbation; the A (h)
// split is KEPT so the recurrent state keeps ~16 mantissa bits.
// Pipeline: 3 LDS staging buffers (24 KB), depth-2 prefetch, counted
// s_waitcnt vmcnt(3) (3 loads/stage; never drain mid-loop).
// Epilogue operands (XT, WiP gather, c4) hoisted under kc0 (R6).
// Bank-conflict-free frag reads via k-segment rotation sg=(s+(row>>1))&3
// applied on the GLOBAL side (LDS dest stays lane-ordered for global_load_lds).
// ---------------------------------------------------------------------------
__global__ __launch_bounds__(512, 2) void fused_step(
    const u16* __restrict__ Ahi, const u16* __restrict__ Alo,
    const u16* __restrict__ Bhi, const u16* __restrict__ Blo,
    const float* __restrict__ bsumP, const float* __restrict__ WiP,
    const int* __restrict__ XT, int t,
    float* __restrict__ c4, u16* __restrict__ Ohi, u16* __restrict__ Olo)
{
    (void)Blo;   // R9: Wh lo correction dropped
    constexpr int KD = 1024;
    // staging per buf (u16): Ahi [0,4096) Alo [4096,8192) Bhi [8192,12288)
    // 3 bufs x 24 KB = 72 KB; epilogue: 8 wave-private tiles 64x33 floats = 67584 B (reuse)
    __shared__ __align__(16) char smem[73728];
    u16* lds = (u16*)smem;
    float* tileb = (float*)smem;

    int bid = blockIdx.x;
    int xcd = bid & 7, rr = bid >> 3;           // rr 0..31
    int m0 = (rr & 1) * 128;
    int n0 = (((rr >> 1) * 8) + xcd) * 128;     // 0..16256
    int tid  = threadIdx.x;
    int lane = tid & 63;
    int wave = tid >> 6;                        // 0..7
    int wm = wave >> 2, wn = wave & 3;          // 2m x 4n
    int quad = lane >> 4, l15 = lane & 15;

    // epilogue addressing (hoisted)
    int bg = m0 + wm * 64 + lane;
    int hxbase = (n0 + wn * 32) >> 4;

    // X row for this step: issued FIRST so the prologue vmcnt(3) drains it
    int xr = XT[t * 256 + bg];

    f32x4 acc[4][2] = {};

    int srow = tid >> 2, ss = tid & 3;
    int sg = (ss + (srow >> 1)) & 3;            // rotated k-segment (global side)
    auto stage = [&](int base, int kc) {
        int k0 = kc * 32;
        size_t ga = (size_t)(m0 + srow) * KD + k0 + sg * 8;
        size_t gb = (size_t)(n0 + srow) * KD + k0 + sg * 8;
        GLD_LDS(Ahi + ga, &lds[base + 0     + tid * 8]);
        GLD_LDS(Alo + ga, &lds[base + 4096  + tid * 8]);
        GLD_LDS(Bhi + gb, &lds[base + 8192  + tid * 8]);
    };

    // frag read offsets (un-rotate the segment): phys = (quad - (row>>1)) & 3
    int aro[4], bro[2];
#pragma unroll
    for (int mi = 0; mi < 4; ++mi) {
        int ar = wm * 64 + mi * 16 + l15;       // 0..127
        aro[mi] = ar * 32 + (((quad - (ar >> 1)) & 3) * 8);
    }
#pragma unroll
    for (int ni = 0; ni < 2; ++ni) {
        int br = wn * 32 + ni * 16 + l15;       // 0..127
        bro[ni] = br * 32 + (((quad - (br >> 1)) & 3) * 8);
    }

    constexpr int NK = KD / 32;
    // prologue: stage kc=0,1 into bufs 0,1 (6 loads); vmcnt(3) completes
    // buf 0 + the xr read, leaving buf 1's 3 loads in flight.
    stage(0, 0);
    stage(12288, 1);
    asm volatile("s_waitcnt vmcnt(3)" ::: "memory");
    __builtin_amdgcn_s_barrier();
    asm volatile("" ::: "memory");

    // issue the scattered epilogue gather NOW (xr already drained — no wait);
    // these 10 loads complete under kc0 and are drained by kc0's vmcnt(3).
    float4 wv[2][4];
    float4 cc[2];
#pragma unroll
    for (int u = 0; u < 2; ++u) {
        const float4* wipp = (const float4*)&WiP[(size_t)xr * 16384 + (hxbase + u) * 16];
#pragma unroll
        for (int k = 0; k < 4; ++k) wv[u][k] = wipp[k];
        cc[u] = *(const float4*)&c4[((size_t)(hxbase + u) * 256 + bg) * 4];
    }

    int basec = 0;                               // u16 base of buf kc%3
    for (int kc = 0; kc < NK; ++kc) {
        short8 afh[4], afl[4], bfh[2];
#pragma unroll
        for (int mi = 0; mi < 4; ++mi) {
            afh[mi] = *(const short8*)&lds[basec + 0    + aro[mi]];
            afl[mi] = *(const short8*)&lds[basec + 4096 + aro[mi]];
        }
#pragma unroll
        for (int ni = 0; ni < 2; ++ni)
            bfh[ni] = *(const short8*)&lds[basec + 8192 + bro[ni]];
        if (kc + 2 < NK) {
            int basen = basec + 24576;           // (kc+2)%3 buffer
            if (basen >= 36864) basen -= 36864;
            stage(basen, kc + 2);
        }
        // 16 MFMAs: term-major hh x8 then lh x8 (dependent-pair distance 8)
#pragma unroll
        for (int mi = 0; mi < 4; ++mi)
#pragma unroll
            for (int ni = 0; ni < 2; ++ni)
                acc[mi][ni] = __builtin_amdgcn_mfma_f32_16x16x32_bf16(afh[mi], bfh[ni], acc[mi][ni], 0, 0, 0);
#pragma unroll
        for (int mi = 0; mi < 4; ++mi)
#pragma unroll
            for (int ni = 0; ni < 2; ++ni)
                acc[mi][ni] = __builtin_amdgcn_mfma_f32_16x16x32_bf16(afl[mi], bfh[ni], acc[mi][ni], 0, 0, 0);

        // counted wait: buf (kc+1)%3's loads (issued at kc-1) must be complete;
        // the 3 loads just issued for kc+2 may remain in flight.
        if (kc + 2 < NK) {
            asm volatile("s_waitcnt vmcnt(3)" ::: "memory");
        } else {
            asm volatile("s_waitcnt vmcnt(0)" ::: "memory");
        }
        __builtin_amdgcn_s_barrier();
        asm volatile("" ::: "memory");

        basec += 12288;
        if (basec >= 36864) basec = 0;
    }

    __syncthreads();   // staging region -> epilogue tile reuse (queues already drained)

    // Phase 1: raw acc -> wave-private tile [64][33]
    float* wt = tileb + wave * (64 * 33);
#pragma unroll
    for (int mi = 0; mi < 4; ++mi)
#pragma unroll
        for (int ni = 0; ni < 2; ++ni)
#pragma unroll
            for (int r = 0; r < 4; ++r) {
                int rl = mi * 16 + quad * 4 + r;    // 0..63
                int cl = ni * 16 + l15;             // 0..31
                wt[rl * 33 + cl] = acc[mi][ni][r];
            }

    // Phase 2: per-lane cell update — all operands already in registers.
#pragma unroll
    for (int u = 0; u < 2; ++u) {
        int hxg = hxbase + u;
        const float* g16 = &wt[lane * 33 + u * 16];
        const float4* bsp = (const float4*)&bsumP[hxg * 16];
        float* cp = &c4[((size_t)hxg * 256 + bg) * 4];
        float ca[4] = {cc[u].x, cc[u].y, cc[u].z, cc[u].w};
        float best = -3.4e38f, csel = 0.0f;
        float cn[4];
#pragma unroll
        for (int k = 0; k < 4; ++k) {
            float4 wvk = wv[u][k];
            float4 bv = bsp[k];
            float gi = (g16[k * 4 + 0] + bv.x) + wvk.x;
            float gf = (g16[k * 4 + 1] + bv.y) + wvk.y;
            float gg = (g16[k * 4 + 2] + bv.z) + wvk.z;
            float go = (g16[k * 4 + 3] + bv.w) + wvk.w;
            float ig = sigf(gi);
            float fg = sigf(gf);
            float tg = tanhf(gg);
            cn[k] = fg * ca[k] + ig * tg;
            if (go > best) { best = go; csel = cn[k]; }   // strict > = first max
        }
        float4 cv = {cn[0], cn[1], cn[2], cn[3]};
        *(float4*)cp = cv;
        float h = sigf(best) * tanhf(csel);
        u32 hi = bf16_rne(h);
        float hif = __uint_as_float(hi << 16);
        u32 lo = bf16_rne(h - hif);
        Ohi[(size_t)bg * 1024 + hxg] = (u16)hi;
        Olo[(size_t)bg * 1024 + hxg] = (u16)lo;
    }
}

// ---------------------------------------------------------------------------
// Logits GEMM (LDS structure): C[256][1024] = h @ Wl + bl. BM=128,BN=128, grid 16.
// (keeps the full 3-term bf16x3 path — one launch, negligible cost)
// ---------------------------------------------------------------------------
__global__ __launch_bounds__(256) void gemm_logits(
    const u16* __restrict__ Ahi, const u16* __restrict__ Alo,
    const u16* __restrict__ Bhi, const u16* __restrict__ Blo,
    float* __restrict__ C, const float* __restrict__ bias)
{
    constexpr int KD = 1024;
    __shared__ u16 lds[2][16384];
    int bid = blockIdx.x;
    int xcd = bid & 7, g = bid >> 3;
    int m0 = g * 128;
    int n0 = xcd * 128;
    int tid  = threadIdx.x;
    int lane = tid & 63;
    int wave = tid >> 6;
    int wm = wave >> 1, wn = wave & 1;
    int quad = lane >> 4, l15 = lane & 15;

    f32x4 acc[4][4] = {};

    auto stage = [&](int buf, int kc) {
        int k0 = kc * 32;
#pragma unroll
        for (int j = 0; j < 2; ++j) {
            int seg = j * 256 + tid;
            int row = seg >> 2, s = seg & 3;
            size_t ga = (size_t)(m0 + row) * KD + k0 + s * 8;
            GLD_LDS(Ahi + ga, &lds[buf][0    + seg * 8]);
            GLD_LDS(Alo + ga, &lds[buf][4096 + seg * 8]);
            size_t gb = (size_t)(n0 + row) * KD + k0 + s * 8;
            GLD_LDS(Bhi + gb, &lds[buf][8192  + seg * 8]);
            GLD_LDS(Blo + gb, &lds[buf][12288 + seg * 8]);
        }
    };

    stage(0, 0);
    constexpr int NK = KD / 32;
    for (int kc = 0; kc < NK; ++kc) {
        __syncthreads();
        if (kc + 1 < NK) stage((kc + 1) & 1, kc + 1);
        int buf = kc & 1;
        short8 afh[4], afl[4], bfh[4], bfl[4];
#pragma unroll
        for (int i = 0; i < 4; ++i) {
            int ar = wm * 64 + i * 16 + l15;
            afh[i] = *(const short8*)&lds[buf][0    + ar * 32 + quad * 8];
            afl[i] = *(const short8*)&lds[buf][4096 + ar * 32 + quad * 8];
            int br = wn * 64 + i * 16 + l15;
            bfh[i] = *(const short8*)&lds[buf][8192  + br * 32 + quad * 8];
            bfl[i] = *(const short8*)&lds[buf][12288 + br * 32 + quad * 8];
        }
#pragma unroll
        for (int mi = 0; mi < 4; ++mi)
#pragma unroll
            for (int ni = 0; ni < 4; ++ni)
                acc[mi][ni] = __builtin_amdgcn_mfma_f32_16x16x32_bf16(afh[mi], bfh[ni], acc[mi][ni], 0, 0, 0);
#pragma unroll
        for (int mi = 0; mi < 4; ++mi)
#pragma unroll
            for (int ni = 0; ni < 4; ++ni)
                acc[mi][ni] = __builtin_amdgcn_mfma_f32_16x16x32_bf16(afh[mi], bfl[ni], acc[mi][ni], 0, 0, 0);
#pragma unroll
        for (int mi = 0; mi < 4; ++mi)
#pragma unroll
            for (int ni = 0; ni < 4; ++ni)
                acc[mi][ni] = __builtin_amdgcn_mfma_f32_16x16x32_bf16(afl[mi], bfh[ni], acc[mi][ni], 0, 0, 0);
    }

#pragma unroll
    for (int mi = 0; mi < 4; ++mi) {
        int rbase = m0 + wm * 64 + mi * 16 + quad * 4;
#pragma unroll
        for (int ni = 0; ni < 4; ++ni) {
            int col = n0 + wn * 64 + ni * 16 + l15;
            float bv = bias[col];
#pragma unroll
            for (int r = 0; r < 4; ++r)
                C[(size_t)(rbase + r) * 1024 + col] = acc[mi][ni][r] + bv;
        }
    }
}

// ---------------------------------------------------------------------------
// Row-wise log_softmax in place over [256][1024]
// ---------------------------------------------------------------------------
__global__ __launch_bounds__(256) void logsoftmax_k(float* __restrict__ io)
{
    int b = blockIdx.x;
    float* row = io + (size_t)b * 1024;
    int tid = threadIdx.x;
    float x0 = row[tid], x1 = row[tid + 256], x2 = row[tid + 512], x3 = row[tid + 768];
    float m = fmaxf(fmaxf(x0, x1), fmaxf(x2, x3));
#pragma unroll
    for (int off = 32; off > 0; off >>= 1) m = fmaxf(m, __shfl_down(m, off, 64));
    __shared__ float sm[4], ss[4];
    if ((tid & 63) == 0) sm[tid >> 6] = m;
    __syncthreads();
    float M = fmaxf(fmaxf(sm[0], sm[1]), fmaxf(sm[2], sm[3]));
    float s = expf(x0 - M) + expf(x1 - M) + expf(x2 - M) + expf(x3 - M);
#pragma unroll
    for (int off = 32; off > 0; off >>= 1) s += __shfl_down(s, off, 64);
    if ((tid & 63) == 0) ss[tid >> 6] = s;
    __syncthreads();
    float L = M + logf(ss[0] + ss[1] + ss[2] + ss[3]);
    row[tid] = x0 - L; row[tid + 256] = x1 - L; row[tid + 512] = x2 - L; row[tid + 768] = x3 - L;
}

// ---------------------------------------------------------------------------
extern "C" void kernel_launch(void* const* d_in, const int* in_sizes, int n_in,
                              void* d_out, int out_size, void* d_ws, size_t ws_size,
                              hipStream_t stream)
{
    const int*   X  = (const int*)d_in[0];
    const float* Wi = (const float*)d_in[1];
    const float* bi = (const float*)d_in[2];
    const float* Wh = (const float*)d_in[3];
    const float* bh = (const float*)d_in[4];
    const float* Wl = (const float*)d_in[5];
    const float* bl = (const float*)d_in[6];
    float* out = (float*)d_out;

    char* p = (char*)d_ws;
    auto alloc = [&](size_t bytes) {
        char* r = p;
        p += (bytes + 255) & ~(size_t)255;
        return r;
    };
    u16*   WhTh = (u16*)alloc((size_t)16384 * 1024 * 2);
    u16*   WhTl = (u16*)alloc((size_t)16384 * 1024 * 2);
    u16*   WlTh = (u16*)alloc((size_t)1024 * 1024 * 2);
    u16*   WlTl = (u16*)alloc((size_t)1024 * 1024 * 2);
    float* WiP  = (float*)alloc((size_t)1024 * 16384 * 4);
    float* c4   = (float*)alloc((size_t)256 * 1024 * 4 * 4);
    u16*   h0h  = (u16*)alloc((size_t)262144 * 2);
    u16*   h0l  = (u16*)alloc((size_t)262144 * 2);
    u16*   h1h  = (u16*)alloc((size_t)262144 * 2);
    u16*   h1l  = (u16*)alloc((size_t)262144 * 2);
    float* bsum  = (float*)alloc((size_t)16384 * 4);
    float* bsumP = (float*)alloc((size_t)16384 * 4);
    int*   XT    = (int*)alloc((size_t)128 * 256 * 4);

    transpose_split<true><<<dim3(256, 16), 256, 0, stream>>>(Wh, WhTh, WhTl, 16384);
    transpose_split<false><<<dim3(16, 16), 256, 0, stream>>>(Wl, WlTh, WlTl, 1024);
    permute_wi<<<dim3(4, 1024), 256, 0, stream>>>(Wi, WiP);
    init_state<<<64, 256, 0, stream>>>(bsum, bsumP, bi, bh);
    transpose_x<<<128, 256, 0, stream>>>(X, XT);

    // Step 0 (h=0, c=0): writes h buffer 1
    cell0<<<1024, 256, 0, stream>>>(bsum, X, Wi, c4, h1h, h1l);

    for (int t = 1; t < 128; ++t) {
        const u16* ih = (t & 1) ? h1h : h0h;
        const u16* il = (t & 1) ? h1l : h0l;
        u16* oh = (t & 1) ? h0h : h1h;
        u16* ol = (t & 1) ? h0l : h1l;
        fused_step<<<256, 512, 0, stream>>>(ih, il, WhTh, WhTl, bsumP, WiP, XT, t, c4, oh, ol);
    }

    // t=127 wrote buffer 0
    gemm_logits<<<16, 256, 0, stream>>>(h0h, h0l, WlTh, WlTl, out, bl);
    logsoftmax_k<<<256, 256, 0, stream>>>(out);
}